// Round 7
// baseline (948.642 us; speedup 1.0000x reference)
//
#include <hip/hip_runtime.h>
#include <math.h>

typedef __bf16 bf16x8 __attribute__((ext_vector_type(8)));
typedef __bf16 bf16x4 __attribute__((ext_vector_type(4)));
typedef float f32x4 __attribute__((ext_vector_type(4)));

#define PI_D 3.14159265358979323846

// Barrier that waits only on LDS traffic (lgkmcnt), NOT vmcnt: outstanding
// global stores keep retiring in the background across phase boundaries.
__device__ __forceinline__ void bar_lds() {
  __builtin_amdgcn_sched_barrier(0);
  asm volatile("s_waitcnt lgkmcnt(0)" ::: "memory");
  __builtin_amdgcn_s_barrier();
  __builtin_amdgcn_sched_barrier(0);
}

// ---------------------------------------------------------------------------
// Prep: pack weights into MFMA-fragment-ordered bf16.
// ---------------------------------------------------------------------------
__global__ void prep_kernel(const float* __restrict__ dir_W,
                            const float* __restrict__ proj1_W,
                            const float* __restrict__ proj2_W,
                            const float* __restrict__ gbf_stds,
                            __bf16* __restrict__ dirP, __bf16* __restrict__ p1P,
                            __bf16* __restrict__ p2P,
                            float* __restrict__ f_az, float* __restrict__ f_po,
                            float* __restrict__ inv_std, float* __restrict__ coef) {
  int tid = threadIdx.x + blockIdx.x * blockDim.x;
  int nth = gridDim.x * blockDim.x;
  for (int o = tid; o < 256 * 256; o += nth) {
    int j = o & 7, l = (o >> 3) & 63, ks = (o >> 9) & 7, nt = o >> 12;
    int d = nt * 16 + (l & 15);
    int s = ks * 32 + (l >> 4) * 8 + j;
    dirP[o] = (__bf16)dir_W[s * 256 + d];
  }
  for (int o = tid; o < 128 * 128; o += nth) {
    int j = o & 7, l = (o >> 3) & 63, ks = (o >> 9) & 3, nt = o >> 11;
    int ko = nt * 16 + (l & 15);
    int ki = ks * 32 + (l >> 4) * 8 + j;
    p1P[o] = (__bf16)proj1_W[ki * 128 + ko];
  }
  for (int o = tid; o < 128 * 256; o += nth) {
    int j = o & 7, l = (o >> 3) & 63, ks = (o >> 9) & 3, nt = o >> 11;
    int d = nt * 16 + (l & 15);
    int k = ks * 32 + (l >> 4) * 8 + j;
    p2P[o] = (__bf16)proj2_W[k * 256 + d];
  }
  if (blockIdx.x == 0 && threadIdx.x < 64) {
    int q = threadIdx.x;
    double l0 = log(2.0 * 1e-4);
    double l1a = log(2.0 * 2.0 * PI_D);
    double l1p = log(2.0 * PI_D);
    double ta = l0 + (l1a - l0) * (double)q / 63.0;
    double tp = l0 + (l1p - l0) * (double)q / 63.0;
    f_az[q] = (float)(2.0 * PI_D / exp(ta));
    f_po[q] = (float)(2.0 * PI_D / exp(tp));
  }
  if (blockIdx.x == 1 && threadIdx.x < 128) {
    int k = threadIdx.x;
    float sd = fabsf(gbf_stds[k]) + 0.01f;
    inv_std[k] = 1.0f / sd;
    coef[k] = (float)(1.0 / (sqrt(2.0 * 3.14159) * (double)sd));
  }
}

// ---------------------------------------------------------------------------
// Node features
// ---------------------------------------------------------------------------
__global__ void node_kernel(const int* __restrict__ an, const float* __restrict__ emb_z,
                            const float* __restrict__ ec, const float* __restrict__ cW,
                            const float* __restrict__ cb, const float* __restrict__ mult_W,
                            const float* __restrict__ charge_W, float* __restrict__ out_node) {
  int bi = blockIdx.x;
  int b = bi >> 8, i = bi & 255;
  int d = threadIdx.x;
  int z = (i == 0) ? 101 : an[b * 255 + i - 1];
  float elec = 0.0f;
  if (i != 0) {
    for (int f = 0; f < 20; ++f) elec += ec[z * 20 + f] * cW[f * 256 + d];
    elec += cb[d];
  }
  float v = emb_z[z * 256 + d] + elec + mult_W[256 + d] + charge_W[d];
  __builtin_nontemporal_store(v, &out_node[(size_t)bi * 256 + d]);
}

// ---------------------------------------------------------------------------
// Fused pair kernel, gbf path then dir path, LDS-transpose store epilogues.
// bufA/bufB (17408B each) are reused as: gauss / h, sin_az / sin_po, and
// 64x64 f32 transpose tiles (16KB, XOR-swizzled: slot ^= row&7).
// ---------------------------------------------------------------------------
__global__ __launch_bounds__(256, 4) void pair_kernel(
    const float* __restrict__ positions, const int* __restrict__ atomic_numbers,
    const float* __restrict__ gbf_means, const float* __restrict__ gbf_mul,
    const float* __restrict__ gbf_bias, const float* __restrict__ proj1_b,
    const float* __restrict__ proj2_b, const float* __restrict__ dir_b,
    const __bf16* __restrict__ dirP, const __bf16* __restrict__ p1P,
    const __bf16* __restrict__ p2P, const float* __restrict__ f_az,
    const float* __restrict__ f_po, const float* __restrict__ inv_stdv,
    const float* __restrict__ coefv, float* __restrict__ out_gbf,
    float* __restrict__ out_dir) {
  __shared__ __align__(16) __bf16 bufA[64 * 136];
  __shared__ __align__(16) __bf16 bufB[64 * 136];
  __shared__ float s_az[64], s_po[64], s_gx[64];

  const int tid = threadIdx.x;
  const int bid = blockIdx.x;
  const int jt = bid & 3;
  const int i = (bid >> 2) & 255;
  const int b = bid >> 10;
  const int j0 = jt * 64;
  const long pairbase = ((long)(b * 256 + i)) * 256 + j0;

  const int lane = tid & 63, wv = tid >> 6;
  const int lr = lane & 15, kb = lane >> 4;

  // fixed staging column per thread
  const int g = tid & 15;
  const bool az = g < 8;
  const int q0 = (g & 7) * 8;
  const int k0g = g * 8;
  const int prow = tid >> 4;

  // transpose-epilogue read mapping
  const int trow = tid >> 2;  // 0..63 output row (pair)
  const int tcq = tid & 3;    // col quarter within 64-col stripe

  // preload this thread's 8 angular freqs
  float ftv[8];
  {
    const float* ft = az ? f_az : f_po;
#pragma unroll
    for (int t = 0; t < 8; ++t) ftv[t] = ft[q0 + t];
  }

  // ---- phase 0: per-pair scalars ----
  if (tid < 64) {
    int p = tid, j = j0 + p;
    float pxi = 0.f, pyi = 0.f, pzi = 0.f, pxj = 0.f, pyj = 0.f, pzj = 0.f;
    if (i != 0) { const float* q = positions + ((size_t)b * 255 + (i - 1)) * 3; pxi = q[0]; pyi = q[1]; pzi = q[2]; }
    if (j != 0) { const float* q = positions + ((size_t)b * 255 + (j - 1)) * 3; pxj = q[0]; pyj = q[1]; pzj = q[2]; }
    float dx = pxj - pxi, dy = pyj - pyi, dz = pzj - pzi;
    float sq = dx * dx + dy * dy + dz * dz;
    float dist = sqrtf(sq + 1e-12f);
    float inv = 1.0f / (dist + 1e-5f);
    float ndx = dx * inv, ndy = dy * inv, ndz = dz * inv;
    bool diag = (i == j);
    float xs = diag ? 1.0f : ndx;
    float ys = diag ? 0.0f : ndy;
    s_az[p] = atan2f(ys, xs);
    float cz = fminf(fmaxf(ndz, -1.0f + 1e-6f), 1.0f - 1e-6f);
    s_po[p] = acosf(cz);
    int zi = (i == 0) ? 101 : atomic_numbers[b * 255 + i - 1];
    int zj = ((j == 0) ? 101 : atomic_numbers[b * 255 + j - 1]) + 128;
    float mul = gbf_mul[zi] + gbf_mul[zj];
    float bia = gbf_bias[zi] + gbf_bias[zj];
    s_gx[p] = mul * dist + bia;
  }
  bar_lds();

  // ============================ GBF PATH ============================
#pragma unroll
  for (int it = 0; it < 4; ++it) {
    int p = prow + it * 16;
    float gx = s_gx[p];
    bf16x8 gv;
#pragma unroll
    for (int t = 0; t < 8; ++t) {
      int k = k0g + t;
      float x = (gx - gbf_means[k]) * inv_stdv[k];
      gv[t] = (__bf16)(exp2f(-0.72134752044448170f * x * x) * coefv[k]);
    }
    *(bf16x8*)(bufA + p * 136 + k0g) = gv;
  }
  bar_lds();

  // ---- proj1 ----
  f32x4 acc1[2][4];
#pragma unroll
  for (int mtl = 0; mtl < 2; ++mtl)
#pragma unroll
    for (int np = 0; np < 4; ++np) acc1[mtl][np] = (f32x4){0.f, 0.f, 0.f, 0.f};
#pragma unroll
  for (int ksl = 0; ksl < 4; ++ksl) {
    bf16x8 bfr[4];
#pragma unroll
    for (int np = 0; np < 4; ++np)
      bfr[np] = *(const bf16x8*)(bufA + (np * 16 + lr) * 136 + ksl * 32 + kb * 8);
#pragma unroll
    for (int mtl = 0; mtl < 2; ++mtl) {
      int mtile = mtl * 4 + wv;
      bf16x8 af = *(const bf16x8*)(p1P + (((size_t)mtile * 4 + ksl) * 64 + lane) * 8);
#pragma unroll
      for (int np = 0; np < 4; ++np)
        acc1[mtl][np] = __builtin_amdgcn_mfma_f32_16x16x32_bf16(af, bfr[np], acc1[mtl][np], 0, 0, 0);
    }
  }

  // ---- GELU -> bufB ----
#pragma unroll
  for (int mtl = 0; mtl < 2; ++mtl) {
    int ko0 = (mtl * 4 + wv) * 16 + kb * 4;
    f32x4 pb = *(const f32x4*)(proj1_b + ko0);
#pragma unroll
    for (int np = 0; np < 4; ++np) {
      f32x4 hv = acc1[mtl][np] + pb;
      bf16x4 hb;
#pragma unroll
      for (int r = 0; r < 4; ++r) {
        float v = hv[r];
        v = 0.5f * v * (1.0f + erff(v * 0.70710678118654752f));
        hb[r] = (__bf16)v;
      }
      *(bf16x4*)(bufB + (np * 16 + lr) * 136 + ko0) = hb;
    }
  }
  bar_lds();

  // ---- proj2 ----
  f32x4 acc2[4][4];
#pragma unroll
  for (int mtl = 0; mtl < 4; ++mtl)
#pragma unroll
    for (int np = 0; np < 4; ++np) acc2[mtl][np] = (f32x4){0.f, 0.f, 0.f, 0.f};
#pragma unroll
  for (int ksl = 0; ksl < 4; ++ksl) {
    bf16x8 bfr[4];
#pragma unroll
    for (int np = 0; np < 4; ++np)
      bfr[np] = *(const bf16x8*)(bufB + (np * 16 + lr) * 136 + ksl * 32 + kb * 8);
#pragma unroll
    for (int mtl = 0; mtl < 4; ++mtl) {
      int mtile = mtl * 4 + wv;
      bf16x8 af = *(const bf16x8*)(p2P + (((size_t)mtile * 4 + ksl) * 64 + lane) * 8);
#pragma unroll
      for (int np = 0; np < 4; ++np)
        acc2[mtl][np] = __builtin_amdgcn_mfma_f32_16x16x32_bf16(af, bfr[np], acc2[mtl][np], 0, 0, 0);
    }
  }

  // ---- gbf epilogue: LDS-transpose -> coalesced 256B-contiguous NT stores --
  {
    const int wslot = wv * 4 + kb;
#pragma unroll
    for (int mtl = 0; mtl < 4; ++mtl) {
      float* tp = (mtl & 1) ? (float*)bufB : (float*)bufA;
      int dcol0 = (mtl * 4 + wv) * 16 + kb * 4;
      f32x4 bias = *(const f32x4*)(proj2_b + dcol0);
#pragma unroll
      for (int np = 0; np < 4; ++np) {
        int row = np * 16 + lr;
        *(f32x4*)(tp + row * 64 + ((wslot ^ (row & 7)) << 2)) = acc2[mtl][np] + bias;
      }
      bar_lds();
#pragma unroll
      for (int q = 0; q < 4; ++q) {
        int slot = tcq * 4 + q;
        f32x4 v = *(const f32x4*)(tp + trow * 64 + ((slot ^ (trow & 7)) << 2));
        __builtin_nontemporal_store(v, (f32x4*)(out_gbf + (pairbase + trow) * 256 + mtl * 64 + slot * 4));
      }
    }
  }
  bar_lds();  // last transpose reads done; bufs free for sinusoids

  // ============================ DIR PATH ============================
#pragma unroll
  for (int it = 0; it < 4; ++it) {
    int p = prow + it * 16;
    float ang = az ? s_az[p] : s_po[p];
    bf16x8 sv, cv;
#pragma unroll
    for (int t = 0; t < 8; ++t) {
      float ph = ang * ftv[t];  // f32 product, same as reference
      double r = (double)ph * 0.15915494309189535;  // /(2*pi) -> revolutions
      double fr = r - rint(r);                      // exact reduction
      float frf = (float)fr;
      sv[t] = (__bf16)__builtin_amdgcn_sinf(frf);
      cv[t] = (__bf16)__builtin_amdgcn_cosf(frf);
    }
    __bf16* base = (az ? bufA : bufB) + p * 136 + q0;
    *(bf16x8*)(base) = sv;
    *(bf16x8*)(base + 64) = cv;
  }
  bar_lds();

  // ---- dir GEMM ----
  f32x4 acc[4][4];
#pragma unroll
  for (int mtl = 0; mtl < 4; ++mtl)
#pragma unroll
    for (int np = 0; np < 4; ++np) acc[mtl][np] = (f32x4){0.f, 0.f, 0.f, 0.f};
#pragma unroll
  for (int ks = 0; ks < 8; ++ks) {
    const __bf16* sbuf = (ks < 4) ? bufA : bufB;
    int ksl = ks & 3;
    bf16x8 bfr[4];
#pragma unroll
    for (int np = 0; np < 4; ++np)
      bfr[np] = *(const bf16x8*)(sbuf + (np * 16 + lr) * 136 + ksl * 32 + kb * 8);
#pragma unroll
    for (int mtl = 0; mtl < 4; ++mtl) {
      int mtile = mtl * 4 + wv;
      bf16x8 af = *(const bf16x8*)(dirP + (((size_t)mtile * 8 + ks) * 64 + lane) * 8);
#pragma unroll
      for (int np = 0; np < 4; ++np)
        acc[mtl][np] = __builtin_amdgcn_mfma_f32_16x16x32_bf16(af, bfr[np], acc[mtl][np], 0, 0, 0);
    }
  }
  bar_lds();  // all waves done reading sinusoid bufs before transpose reuse

  // ---- dir epilogue: LDS-transpose -> coalesced NT stores ----
  {
    const int wslot = wv * 4 + kb;
#pragma unroll
    for (int mtl = 0; mtl < 4; ++mtl) {
      float* tp = (mtl & 1) ? (float*)bufB : (float*)bufA;
      int dcol0 = (mtl * 4 + wv) * 16 + kb * 4;
      f32x4 bias = *(const f32x4*)(dir_b + dcol0);
#pragma unroll
      for (int np = 0; np < 4; ++np) {
        int row = np * 16 + lr;
        *(f32x4*)(tp + row * 64 + ((wslot ^ (row & 7)) << 2)) = acc[mtl][np] + bias;
      }
      bar_lds();
#pragma unroll
      for (int q = 0; q < 4; ++q) {
        int slot = tcq * 4 + q;
        f32x4 v = *(const f32x4*)(tp + trow * 64 + ((slot ^ (trow & 7)) << 2));
        __builtin_nontemporal_store(v, (f32x4*)(out_dir + (pairbase + trow) * 256 + mtl * 64 + slot * 4));
      }
    }
  }
}

extern "C" void kernel_launch(void* const* d_in, const int* in_sizes, int n_in,
                              void* d_out, int out_size, void* d_ws, size_t ws_size,
                              hipStream_t stream) {
  const float* positions = (const float*)d_in[0];
  const int* atomic_numbers = (const int*)d_in[1];
  const float* emb_z = (const float*)d_in[2];
  const float* electron_config = (const float*)d_in[3];
  const float* config_W = (const float*)d_in[4];
  const float* config_b = (const float*)d_in[5];
  const float* mult_W = (const float*)d_in[6];
  const float* charge_W = (const float*)d_in[7];
  const float* gbf_means = (const float*)d_in[8];
  const float* gbf_stds = (const float*)d_in[9];
  const float* gbf_mul = (const float*)d_in[10];
  const float* gbf_bias = (const float*)d_in[11];
  const float* proj1_W = (const float*)d_in[12];
  const float* proj1_b = (const float*)d_in[13];
  const float* proj2_W = (const float*)d_in[14];
  const float* proj2_b = (const float*)d_in[15];
  const float* dir_W = (const float*)d_in[16];
  const float* dir_b = (const float*)d_in[17];

  float* out = (float*)d_out;
  float* out_node = out;
  float* out_gbf = out + 262144;
  float* out_dir = out + 262144 + 67108864;

  char* ws = (char*)d_ws;
  __bf16* dirP = (__bf16*)(ws);
  __bf16* p1P = (__bf16*)(ws + 131072);
  __bf16* p2P = (__bf16*)(ws + 131072 + 32768);
  float* f_az = (float*)(ws + 229376);
  float* f_po = (float*)(ws + 229376 + 256);
  float* inv_std = (float*)(ws + 229376 + 512);
  float* coef = (float*)(ws + 229376 + 1024);

  prep_kernel<<<64, 256, 0, stream>>>(dir_W, proj1_W, proj2_W, gbf_stds, dirP, p1P,
                                      p2P, f_az, f_po, inv_std, coef);
  node_kernel<<<1024, 256, 0, stream>>>(atomic_numbers, emb_z, electron_config,
                                        config_W, config_b, mult_W, charge_W, out_node);
  pair_kernel<<<4096, 256, 0, stream>>>(positions, atomic_numbers, gbf_means, gbf_mul,
                                        gbf_bias, proj1_b, proj2_b, dir_b, dirP, p1P,
                                        p2P, f_az, f_po, inv_std, coef, out_gbf, out_dir);
}

// Round 8
// 157.782 us; speedup vs baseline: 6.0124x; 6.0124x over previous
//
#include <hip/hip_runtime.h>
#include <math.h>

typedef __bf16 bf16x8 __attribute__((ext_vector_type(8)));
typedef __bf16 bf16x4 __attribute__((ext_vector_type(4)));
typedef float f32x4 __attribute__((ext_vector_type(4)));
typedef float f32x2 __attribute__((ext_vector_type(2)));

#define PI_D 3.14159265358979323846
// f32 two-term split of 1/(2*pi): IH = f32(1/2pi), IL = 1/2pi - IH
#define IH 0.15915494f
#define IL 6.4206383e-9f

// Barrier waiting only on LDS (lgkmcnt) — outstanding global stores keep
// retiring in the background instead of draining at every phase boundary.
__device__ __forceinline__ void bar_lds() {
  __builtin_amdgcn_sched_barrier(0);
  asm volatile("s_waitcnt lgkmcnt(0)" ::: "memory");
  __builtin_amdgcn_s_barrier();
  __builtin_amdgcn_sched_barrier(0);
}

// ---------------------------------------------------------------------------
// Prep: pack weights into MFMA A-fragment order with vector writes, build
// freq table (f32, matching reference rounding) and folded gauss tables.
// ---------------------------------------------------------------------------
__global__ void prep_kernel(const float* __restrict__ dir_W,
                            const float* __restrict__ proj1_W,
                            const float* __restrict__ proj2_W,
                            const float* __restrict__ gbf_stds,
                            const float* __restrict__ gbf_means,
                            __bf16* __restrict__ dirP, __bf16* __restrict__ p1P,
                            __bf16* __restrict__ p2P,
                            float* __restrict__ f_az, float* __restrict__ f_po,
                            f32x2* __restrict__ gAB, float* __restrict__ gcoef) {
  int tid = threadIdx.x + blockIdx.x * blockDim.x;
  int nth = gridDim.x * blockDim.x;
  // dirP: 8192 fragment rows of 8 (value = dir_W[s*256+d], s=ks*32+(l>>4)*8+j)
  for (int o8 = tid; o8 < 8192; o8 += nth) {
    int l = o8 & 63, ks = (o8 >> 6) & 7, nt = o8 >> 9;
    int d = nt * 16 + (l & 15);
    int s0 = ks * 32 + (l >> 4) * 8;
    bf16x8 v;
#pragma unroll
    for (int j = 0; j < 8; ++j) v[j] = (__bf16)dir_W[(s0 + j) * 256 + d];
    *(bf16x8*)(dirP + o8 * 8) = v;
  }
  // p1P: 2048 rows
  for (int o8 = tid; o8 < 2048; o8 += nth) {
    int l = o8 & 63, ks = (o8 >> 6) & 3, nt = o8 >> 8;
    int ko = nt * 16 + (l & 15);
    int k0 = ks * 32 + (l >> 4) * 8;
    bf16x8 v;
#pragma unroll
    for (int j = 0; j < 8; ++j) v[j] = (__bf16)proj1_W[(k0 + j) * 128 + ko];
    *(bf16x8*)(p1P + o8 * 8) = v;
  }
  // p2P: 4096 rows
  for (int o8 = tid; o8 < 4096; o8 += nth) {
    int l = o8 & 63, ks = (o8 >> 6) & 3, nt = o8 >> 8;
    int d = nt * 16 + (l & 15);
    int k0 = ks * 32 + (l >> 4) * 8;
    bf16x8 v;
#pragma unroll
    for (int j = 0; j < 8; ++j) v[j] = (__bf16)proj2_W[(k0 + j) * 256 + d];
    *(bf16x8*)(p2P + o8 * 8) = v;
  }
  if (blockIdx.x == 0 && threadIdx.x < 64) {
    int q = threadIdx.x;
    double l0 = log(2.0 * 1e-4);
    double l1a = log(2.0 * 2.0 * PI_D);
    double l1p = log(2.0 * PI_D);
    double ta = l0 + (l1a - l0) * (double)q / 63.0;
    double tp = l0 + (l1p - l0) * (double)q / 63.0;
    f_az[q] = (float)(2.0 * PI_D / exp(ta));   // f32 freq, as reference
    f_po[q] = (float)(2.0 * PI_D / exp(tp));
  }
  if (blockIdx.x == 1 && threadIdx.x < 128) {
    int k = threadIdx.x;
    double sd = (double)(fabsf(gbf_stds[k]) + 0.01f);
    double c = sqrt(0.7213475204444817);  // sqrt(0.5*log2(e))
    double A = c / sd;
    f32x2 ab;
    ab.x = (float)A;
    ab.y = (float)(-A * (double)gbf_means[k]);
    gAB[k] = ab;
    gcoef[k] = (float)(1.0 / (sqrt(2.0 * 3.14159) * sd));
  }
}

// ---------------------------------------------------------------------------
// Node features
// ---------------------------------------------------------------------------
__global__ void node_kernel(const int* __restrict__ an, const float* __restrict__ emb_z,
                            const float* __restrict__ ec, const float* __restrict__ cW,
                            const float* __restrict__ cb, const float* __restrict__ mult_W,
                            const float* __restrict__ charge_W, float* __restrict__ out_node) {
  int bi = blockIdx.x;
  int b = bi >> 8, i = bi & 255;
  int d = threadIdx.x;
  int z = (i == 0) ? 101 : an[b * 255 + i - 1];
  float elec = 0.0f;
  if (i != 0) {
    for (int f = 0; f < 20; ++f) elec += ec[z * 20 + f] * cW[f * 256 + d];
    elec += cb[d];
  }
  float v = emb_z[z * 256 + d] + elec + mult_W[256 + d] + charge_W[d];
  __builtin_nontemporal_store(v, &out_node[(size_t)bi * 256 + d]);
}

// ---------------------------------------------------------------------------
// Fused pair kernel (r5 structure): dir (two K-halves) then gbf, one
// [64][136] bf16 LDS buffer, direct NT f32x4 stores (16 full lines/inst).
// ---------------------------------------------------------------------------
__global__ __launch_bounds__(256, 4) void pair_kernel(
    const float* __restrict__ positions, const int* __restrict__ atomic_numbers,
    const float* __restrict__ gbf_mul, const float* __restrict__ gbf_bias,
    const float* __restrict__ proj1_b, const float* __restrict__ proj2_b,
    const float* __restrict__ dir_b, const __bf16* __restrict__ dirP,
    const __bf16* __restrict__ p1P, const __bf16* __restrict__ p2P,
    const float* __restrict__ f_az, const float* __restrict__ f_po,
    const f32x2* __restrict__ gAB, const float* __restrict__ gcoef,
    float* __restrict__ out_gbf, float* __restrict__ out_dir) {
  __shared__ __align__(16) __bf16 buf[64 * 136];
  __shared__ float s_az[64], s_po[64], s_gx[64];

  const int tid = threadIdx.x;
  const int bid = blockIdx.x;
  const int jt = bid & 3;
  const int i = (bid >> 2) & 255;
  const int b = bid >> 10;
  const int j0 = jt * 64;
  const long pairbase = ((long)(b * 256 + i)) * 256 + j0;

  const int lane = tid & 63, wv = tid >> 6;
  const int lr = lane & 15, kb = lane >> 4;

  // fixed staging columns
  const int q8 = (tid & 7) * 8;   // sinusoid freq group (per half)
  const int pr2 = tid >> 3;       // 0..31 (+32*it)
  const int k0g = (tid & 15) * 8; // gauss k group
  const int prow = tid >> 4;      // 0..15 (+16*it)

  // ---- phase 0: per-pair scalars ----
  if (tid < 64) {
    int p = tid, j = j0 + p;
    float pxi = 0.f, pyi = 0.f, pzi = 0.f, pxj = 0.f, pyj = 0.f, pzj = 0.f;
    if (i != 0) { const float* q = positions + ((size_t)b * 255 + (i - 1)) * 3; pxi = q[0]; pyi = q[1]; pzi = q[2]; }
    if (j != 0) { const float* q = positions + ((size_t)b * 255 + (j - 1)) * 3; pxj = q[0]; pyj = q[1]; pzj = q[2]; }
    float dx = pxj - pxi, dy = pyj - pyi, dz = pzj - pzi;
    float sq = dx * dx + dy * dy + dz * dz;
    float dist = sqrtf(sq + 1e-12f);
    float inv = 1.0f / (dist + 1e-5f);
    float ndx = dx * inv, ndy = dy * inv, ndz = dz * inv;
    bool diag = (i == j);
    float xs = diag ? 1.0f : ndx;
    float ys = diag ? 0.0f : ndy;
    s_az[p] = atan2f(ys, xs);
    float cz = fminf(fmaxf(ndz, -1.0f + 1e-6f), 1.0f - 1e-6f);
    s_po[p] = acosf(cz);
    int zi = (i == 0) ? 101 : atomic_numbers[b * 255 + i - 1];
    int zj = ((j == 0) ? 101 : atomic_numbers[b * 255 + j - 1]) + 128;
    float mul = gbf_mul[zi] + gbf_mul[zj];
    float bia = gbf_bias[zi] + gbf_bias[zj];
    s_gx[p] = mul * dist + bia;
  }
  bar_lds();

  // ================= DIR PATH (two K-halves through one buf) =================
  f32x4 acc[4][4];
#pragma unroll
  for (int mtl = 0; mtl < 4; ++mtl)
#pragma unroll
    for (int np = 0; np < 4; ++np) acc[mtl][np] = (f32x4){0.f, 0.f, 0.f, 0.f};

  for (int half = 0; half < 2; ++half) {
    const float* ft = half ? f_po : f_az;
    float fv[8];
#pragma unroll
    for (int t = 0; t < 8; ++t) fv[t] = ft[q8 + t];
#pragma unroll
    for (int it = 0; it < 2; ++it) {
      int p = pr2 + it * 32;
      float ang = half ? s_po[p] : s_az[p];
      bf16x8 sv, cv;
#pragma unroll
      for (int t = 0; t < 8; ++t) {
        float ph = ang * fv[t];                     // f32 product, as reference
        float n = __builtin_rintf(ph * IH);
        float fr = __builtin_fmaf(ph, IH, -n) + ph * IL;  // exact CW reduction
        sv[t] = (__bf16)__builtin_amdgcn_sinf(fr);  // sin(2*pi*x)
        cv[t] = (__bf16)__builtin_amdgcn_cosf(fr);
      }
      *(bf16x8*)(buf + p * 136 + q8) = sv;
      *(bf16x8*)(buf + p * 136 + 64 + q8) = cv;
    }
    bar_lds();
#pragma unroll
    for (int ksl = 0; ksl < 4; ++ksl) {
      int ks = half * 4 + ksl;
      bf16x8 bfr[4];
#pragma unroll
      for (int np = 0; np < 4; ++np)
        bfr[np] = *(const bf16x8*)(buf + (np * 16 + lr) * 136 + ksl * 32 + kb * 8);
#pragma unroll
      for (int mtl = 0; mtl < 4; ++mtl) {
        int mtile = mtl * 4 + wv;
        bf16x8 af = *(const bf16x8*)(dirP + (((size_t)mtile * 8 + ks) * 64 + lane) * 8);
#pragma unroll
        for (int np = 0; np < 4; ++np)
          acc[mtl][np] = __builtin_amdgcn_mfma_f32_16x16x32_bf16(af, bfr[np], acc[mtl][np], 0, 0, 0);
      }
    }
    bar_lds();
  }

  // prefetch gauss tables BEFORE the store burst (vmcnt is FIFO: loads issued
  // after stores would wait for store acks)
  f32x2 abv[8];
  float gcv[8];
#pragma unroll
  for (int t = 0; t < 8; ++t) { abv[t] = gAB[k0g + t]; gcv[t] = gcoef[k0g + t]; }

  // ---- dir epilogue: NT f32x4 (kb-group => 16 full 64B lines per inst) ----
#pragma unroll
  for (int mtl = 0; mtl < 4; ++mtl) {
    int dcol0 = (mtl * 4 + wv) * 16 + kb * 4;
    f32x4 bias = *(const f32x4*)(dir_b + dcol0);
#pragma unroll
    for (int np = 0; np < 4; ++np) {
      f32x4 v = acc[mtl][np] + bias;
      __builtin_nontemporal_store(v, (f32x4*)(out_dir + (pairbase + np * 16 + lr) * 256 + dcol0));
    }
  }

  // ============================ GBF PATH ============================
#pragma unroll
  for (int it = 0; it < 4; ++it) {
    int p = prow + it * 16;
    float gx = s_gx[p];
    bf16x8 gv;
#pragma unroll
    for (int t = 0; t < 8; ++t) {
      float y = __builtin_fmaf(gx, abv[t].x, abv[t].y);
      gv[t] = (__bf16)(exp2f(-y * y) * gcv[t]);
    }
    *(bf16x8*)(buf + p * 136 + k0g) = gv;
  }
  bar_lds();

  // ---- proj1 ----
  f32x4 acc1[2][4];
#pragma unroll
  for (int mtl = 0; mtl < 2; ++mtl)
#pragma unroll
    for (int np = 0; np < 4; ++np) acc1[mtl][np] = (f32x4){0.f, 0.f, 0.f, 0.f};
#pragma unroll
  for (int ksl = 0; ksl < 4; ++ksl) {
    bf16x8 bfr[4];
#pragma unroll
    for (int np = 0; np < 4; ++np)
      bfr[np] = *(const bf16x8*)(buf + (np * 16 + lr) * 136 + ksl * 32 + kb * 8);
#pragma unroll
    for (int mtl = 0; mtl < 2; ++mtl) {
      int mtile = mtl * 4 + wv;
      bf16x8 af = *(const bf16x8*)(p1P + (((size_t)mtile * 4 + ksl) * 64 + lane) * 8);
#pragma unroll
      for (int np = 0; np < 4; ++np)
        acc1[mtl][np] = __builtin_amdgcn_mfma_f32_16x16x32_bf16(af, bfr[np], acc1[mtl][np], 0, 0, 0);
    }
  }
  bar_lds();  // gauss fully consumed before h overwrites buf

  // ---- GELU -> buf ----
#pragma unroll
  for (int mtl = 0; mtl < 2; ++mtl) {
    int ko0 = (mtl * 4 + wv) * 16 + kb * 4;
    f32x4 pb = *(const f32x4*)(proj1_b + ko0);
#pragma unroll
    for (int np = 0; np < 4; ++np) {
      f32x4 hv = acc1[mtl][np] + pb;
      bf16x4 hb;
#pragma unroll
      for (int r = 0; r < 4; ++r) {
        float v = hv[r];
        v = 0.5f * v * (1.0f + erff(v * 0.70710678118654752f));
        hb[r] = (__bf16)v;
      }
      *(bf16x4*)(buf + (np * 16 + lr) * 136 + ko0) = hb;
    }
  }
  bar_lds();

  // ---- proj2 ----
  f32x4 acc2[4][4];
#pragma unroll
  for (int mtl = 0; mtl < 4; ++mtl)
#pragma unroll
    for (int np = 0; np < 4; ++np) acc2[mtl][np] = (f32x4){0.f, 0.f, 0.f, 0.f};
#pragma unroll
  for (int ksl = 0; ksl < 4; ++ksl) {
    bf16x8 bfr[4];
#pragma unroll
    for (int np = 0; np < 4; ++np)
      bfr[np] = *(const bf16x8*)(buf + (np * 16 + lr) * 136 + ksl * 32 + kb * 8);
#pragma unroll
    for (int mtl = 0; mtl < 4; ++mtl) {
      int mtile = mtl * 4 + wv;
      bf16x8 af = *(const bf16x8*)(p2P + (((size_t)mtile * 4 + ksl) * 64 + lane) * 8);
#pragma unroll
      for (int np = 0; np < 4; ++np)
        acc2[mtl][np] = __builtin_amdgcn_mfma_f32_16x16x32_bf16(af, bfr[np], acc2[mtl][np], 0, 0, 0);
    }
  }
  // ---- gbf epilogue ----
#pragma unroll
  for (int mtl = 0; mtl < 4; ++mtl) {
    int dcol0 = (mtl * 4 + wv) * 16 + kb * 4;
    f32x4 bias = *(const f32x4*)(proj2_b + dcol0);
#pragma unroll
    for (int np = 0; np < 4; ++np) {
      f32x4 v = acc2[mtl][np] + bias;
      __builtin_nontemporal_store(v, (f32x4*)(out_gbf + (pairbase + np * 16 + lr) * 256 + dcol0));
    }
  }
}

extern "C" void kernel_launch(void* const* d_in, const int* in_sizes, int n_in,
                              void* d_out, int out_size, void* d_ws, size_t ws_size,
                              hipStream_t stream) {
  const float* positions = (const float*)d_in[0];
  const int* atomic_numbers = (const int*)d_in[1];
  const float* emb_z = (const float*)d_in[2];
  const float* electron_config = (const float*)d_in[3];
  const float* config_W = (const float*)d_in[4];
  const float* config_b = (const float*)d_in[5];
  const float* mult_W = (const float*)d_in[6];
  const float* charge_W = (const float*)d_in[7];
  const float* gbf_means = (const float*)d_in[8];
  const float* gbf_stds = (const float*)d_in[9];
  const float* gbf_mul = (const float*)d_in[10];
  const float* gbf_bias = (const float*)d_in[11];
  const float* proj1_W = (const float*)d_in[12];
  const float* proj1_b = (const float*)d_in[13];
  const float* proj2_W = (const float*)d_in[14];
  const float* proj2_b = (const float*)d_in[15];
  const float* dir_W = (const float*)d_in[16];
  const float* dir_b = (const float*)d_in[17];

  float* out = (float*)d_out;
  float* out_node = out;
  float* out_gbf = out + 262144;
  float* out_dir = out + 262144 + 67108864;

  char* ws = (char*)d_ws;
  __bf16* dirP = (__bf16*)(ws);
  __bf16* p1P = (__bf16*)(ws + 131072);
  __bf16* p2P = (__bf16*)(ws + 163840);
  float* f_az = (float*)(ws + 229376);
  float* f_po = (float*)(ws + 229376 + 256);
  f32x2* gAB = (f32x2*)(ws + 229376 + 512);
  float* gcoef = (float*)(ws + 229376 + 1536);

  prep_kernel<<<64, 256, 0, stream>>>(dir_W, proj1_W, proj2_W, gbf_stds, gbf_means,
                                      dirP, p1P, p2P, f_az, f_po, gAB, gcoef);
  node_kernel<<<1024, 256, 0, stream>>>(atomic_numbers, emb_z, electron_config,
                                        config_W, config_b, mult_W, charge_W, out_node);
  pair_kernel<<<4096, 256, 0, stream>>>(positions, atomic_numbers, gbf_mul, gbf_bias,
                                        proj1_b, proj2_b, dir_b, dirP, p1P, p2P,
                                        f_az, f_po, gAB, gcoef, out_gbf, out_dir);
}